// Round 3
// baseline (387.474 us; speedup 1.0000x reference)
//
#include <hip/hip_runtime.h>
#include <hip/hip_bf16.h>
#include <cmath>

// out[b,o] = max(softplus(log_scale[o]),1e-4) * sum_k x[b,k]*W[o,k] + bias[o]
// B=32, K=N=8192, W ternary int32 [N,K] row-major => memory-bound on W (256 MB/launch).
// Round 3: barrier-free wave-autonomous K-loop. Each wave stages only its own 16
// W-rows (int32 -> bf16 before LDS write), no __syncthreads in the loop, so the
// compiler emits fine-grained vmcnt and prefetched loads stay in flight across
// compute. KSPLIT=8 -> 1024 blocks -> 4 blocks/CU (16 waves) for overlap.

#define K_SZ   8192
#define N_SZ   8192
#define B_SZ   32
#define KSPLIT 8
#define KSPAN  (K_SZ / KSPLIT)   // 1024 k per block
#define BK     128               // k ints per staged step
#define STEPS  (KSPAN / BK)      // 8
#define BN     64                // output rows per block (16 per wave)
#define LDB    136               // LDS row stride in bf16 (128 + 8 pad: bank-spread)

typedef __attribute__((ext_vector_type(8))) short bf16x8;   // MFMA A/B frag
typedef __attribute__((ext_vector_type(4))) float f32x4;    // MFMA C/D frag

// fp32 pair -> packed bf16 (round-half-up), lo in low 16
__device__ __forceinline__ unsigned pack_rn(float lo, float hi) {
  unsigned ul = __builtin_bit_cast(unsigned, lo) + 0x8000u;
  unsigned uh = __builtin_bit_cast(unsigned, hi) + 0x8000u;
  return (ul >> 16) | (uh & 0xFFFF0000u);
}
// ternary int pair -> packed bf16 (exact: -1,0,1 have <=8-bit mantissas)
__device__ __forceinline__ unsigned pack_w(int w0, int w1) {
  unsigned u0 = __builtin_bit_cast(unsigned, (float)w0);
  unsigned u1 = __builtin_bit_cast(unsigned, (float)w1);
  return (u0 >> 16) | (u1 & 0xFFFF0000u);
}

// Rearrange X fp32[32,8192] -> Xr bf16 chunks in MFMA A-frag order.
// Chunk c = kb*2 + mt (kb = 32-k block 0..255, mt = m-tile 0..1): 1 KB where
// lane l holds X[mt*16 + (l&15)][kb*32 + (l>>4)*8 .. +8] as bf16x8.
__global__ void xprep(const float* __restrict__ X, uint4* __restrict__ Xr) {
  int t = blockIdx.x * blockDim.x + threadIdx.x;   // 0..32767
  int lane = t & 63;
  int chunk = t >> 6;                              // 0..511
  int kb = chunk >> 1;
  int mt = chunk & 1;
  int row = mt * 16 + (lane & 15);
  int k0 = kb * 32 + (lane >> 4) * 8;
  const float* p = X + (size_t)row * K_SZ + k0;
  float4 a = *(const float4*)p;
  float4 b = *(const float4*)(p + 4);
  uint4 o;
  o.x = pack_rn(a.x, a.y); o.y = pack_rn(a.z, a.w);
  o.z = pack_rn(b.x, b.y); o.w = pack_rn(b.z, b.w);
  Xr[t] = o;   // coalesced
}

__global__ __launch_bounds__(256, 4) void tmm(
    const int*   __restrict__ W,
    const uint4* __restrict__ Xr,
    const float* __restrict__ log_scale,
    const float* __restrict__ bias,
    float*       __restrict__ out) {
  // per-wave private LDS: 16 rows x LDB bf16 = 4352 B; x4 waves = 17408 B/block
  __shared__ unsigned short lds[4][16 * LDB];

  const int tid  = threadIdx.x;
  const int w    = tid >> 6;       // wave 0..3 -> n-tile
  const int lane = tid & 63;
  const int q    = lane >> 4;
  const int r    = lane & 15;
  const int nb   = blockIdx.x * BN;
  const int kh   = blockIdx.y;     // k-split slice

  // --- W staging: instr j (0..7) loads rows (2j + lane/32), ints 4*(lane&31).
  // Half-wave-contiguous 512 B spans -> 2 segments/instr.
  const int srow = lane >> 5;
  const int skof = 4 * (lane & 31);
  const int* gW = W + (size_t)(nb + w * 16 + srow) * K_SZ + (size_t)kh * KSPAN + skof;
  unsigned short* lw = &lds[w][0];
  const int wofs = srow * LDB + skof;   // bf16 units; +2j*LDB per instr j

  // prologue: step-0 W loads
  int4 wr[8];
  #pragma unroll
  for (int j = 0; j < 8; ++j) wr[j] = *(const int4*)(gW + (size_t)j * 2 * K_SZ);

  f32x4 acc0 = {0.f,0.f,0.f,0.f};   // m-tile 0 (batch 0..15)
  f32x4 acc1 = {0.f,0.f,0.f,0.f};   // m-tile 1 (batch 16..31)
  const int rb = r * LDB;
  const int kb_blk = kh * (KSPAN / 32);   // base 32-k chunk index

  for (int step = 0; step < STEPS; ++step) {
    // convert current W regs -> packed bf16 (waits vmcnt on wr only)
    uint2 p[8];
    #pragma unroll
    for (int j = 0; j < 8; ++j) {
      p[j].x = pack_w(wr[j].x, wr[j].y);
      p[j].y = pack_w(wr[j].z, wr[j].w);
    }
    // issue next-step W loads ASAP -- in flight across LDS + compute below
    if (step + 1 < STEPS) {
      const int* g = gW + (step + 1) * BK;
      #pragma unroll
      for (int j = 0; j < 8; ++j) wr[j] = *(const int4*)(g + (size_t)j * 2 * K_SZ);
    }
    // stage converted W into this wave's LDS region (in-order vs our own reads)
    #pragma unroll
    for (int j = 0; j < 8; ++j)
      *(uint2*)&lw[wofs + j * 2 * LDB] = p[j];

    // A-frags for this step (Xr is 512 KB: L1/L2-hot)
    const int kb0 = kb_blk + step * 4;
    uint4 am[4][2];
    #pragma unroll
    for (int s = 0; s < 4; ++s) {
      am[s][0] = Xr[(size_t)((kb0 + s) * 2 + 0) * 64 + lane];
      am[s][1] = Xr[(size_t)((kb0 + s) * 2 + 1) * 64 + lane];
    }

    // compute: 4 sub-steps x (1 ds_read_b128 + 2 MFMA)
    #pragma unroll
    for (int s = 0; s < 4; ++s) {
      bf16x8 Bf = *(const bf16x8*)&lw[rb + s * 32 + q * 8];
      acc0 = __builtin_amdgcn_mfma_f32_16x16x32_bf16(
                 __builtin_bit_cast(bf16x8, am[s][0]), Bf, acc0, 0, 0, 0);
      acc1 = __builtin_amdgcn_mfma_f32_16x16x32_bf16(
                 __builtin_bit_cast(bf16x8, am[s][1]), Bf, acc1, 0, 0, 0);
    }
  }

  // epilogue: scale + bias; k-split combine via fp32 atomics into zeroed out
  const int o = nb + w * 16 + r;    // C/D: col = lane&15
  float sp    = log1pf(expf(log_scale[o]));
  float scale = fmaxf(sp, 1e-4f);
  float badd  = (kh == 0) ? bias[o] : 0.f;
  #pragma unroll
  for (int rg = 0; rg < 4; ++rg) {
    int b0 = q * 4 + rg;            // C/D: row = (lane>>4)*4 + reg
    atomicAdd(&out[(size_t)b0 * N_SZ + o],        acc0[rg] * scale + badd);
    atomicAdd(&out[(size_t)(b0 + 16) * N_SZ + o], acc1[rg] * scale + badd);
  }
}

extern "C" void kernel_launch(void* const* d_in, const int* in_sizes, int n_in,
                              void* d_out, int out_size, void* d_ws, size_t ws_size,
                              hipStream_t stream) {
  const float* X  = (const float*)d_in[0];
  const float* ls = (const float*)d_in[1];
  const float* bs = (const float*)d_in[2];
  const int*   W  = (const int*)d_in[3];
  float* out = (float*)d_out;
  uint4* Xr = (uint4*)d_ws;   // 512 KB of ws

  hipMemsetAsync(out, 0, (size_t)B_SZ * N_SZ * sizeof(float), stream);
  xprep<<<128, 256, 0, stream>>>(X, Xr);
  dim3 grid(N_SZ / BN, KSPLIT);
  tmm<<<grid, 256, 0, stream>>>(W, Xr, ls, bs, out);
}